// Round 9
// baseline (301.310 us; speedup 1.0000x reference)
//
#include <hip/hip_runtime.h>

typedef unsigned short u16;
typedef unsigned int u32;
typedef __bf16 bf16x8 __attribute__((ext_vector_type(8)));
typedef float f32x4 __attribute__((ext_vector_type(4)));

#define DIMS 2048
#define SEQ 2048
#define BATCH 2
#define NH 32
#define NG 2
#define DH 64
#define MROWS (BATCH * SEQ)  /* 4096 */
#define KVD (NG * DH)        /* 128 */

#define SCL2 (0.125f * 1.44269504088896f) /* 1/sqrt(64) * log2(e) */

__device__ __forceinline__ u16 f2bf(float f) {
  u32 u = __float_as_uint(f);
  u32 r = u + 0x7fffu + ((u >> 16) & 1u);
  return (u16)(r >> 16);
}
__device__ __forceinline__ u32 pack2(float a, float b) {
  return (u32)f2bf(a) | ((u32)f2bf(b) << 16);
}
// packed f32->bf16x2 (RNE), single instruction on gfx950
__device__ __forceinline__ u32 cvtpk(float a, float b) {
#if __has_builtin(__builtin_amdgcn_cvt_pk_bf16_f32)
  typedef __bf16 bf16x2 __attribute__((ext_vector_type(2)));
  union {
    bf16x2 v;
    u32 u;
  } r;
  r.v = __builtin_amdgcn_cvt_pk_bf16_f32(a, b);
  return r.u;
#else
  return pack2(a, b);
#endif
}
// async global->LDS, 16B/lane. LDS dest = wave-uniform base + lane*16;
// global source address is PER-LANE (vector address).
__device__ __forceinline__ void glds16(const u16* g, u16* l) {
  __builtin_amdgcn_global_load_lds(
      (const __attribute__((address_space(1))) void*)g,
      (__attribute__((address_space(3))) void*)l, 16, 0, 0);
}

// ---------------- prep: RMS_split pre-norm (blocks 0..4095) + fp32->bf16
// weight conversion (blocks 4096..12799) in ONE dispatch.
__global__ __launch_bounds__(256) void prep_kernel(
    const float* __restrict__ x, const float* __restrict__ ns,
    const float* __restrict__ ss, u16* __restrict__ h,
    const float* __restrict__ Wq, const float* __restrict__ Wo,
    const float* __restrict__ Wk, const float* __restrict__ Wv,
    u16* __restrict__ bqkv, u16* __restrict__ bWo) {
  const int bx = blockIdx.x;
  const int tid = threadIdx.x;
  if (bx < 4096) {
    // RMS_split: h = bf16( ns*x/(||x||/sqrt(d)+eps)*ss )
    const float* xr = x + (size_t)bx * DIMS;
    float4 v0 = ((const float4*)xr)[tid];
    float4 v1 = ((const float4*)xr)[tid + 256];
    float s = v0.x * v0.x + v0.y * v0.y + v0.z * v0.z + v0.w * v0.w +
              v1.x * v1.x + v1.y * v1.y + v1.z * v1.z + v1.w * v1.w;
#pragma unroll
    for (int d = 1; d < 64; d <<= 1) s += __shfl_xor(s, d, 64);
    __shared__ float red[4];
    if ((tid & 63) == 0) red[tid >> 6] = s;
    __syncthreads();
    float tot = red[0] + red[1] + red[2] + red[3];
    float inv = 1.0f / (sqrtf(tot * (1.0f / DIMS)) + 1e-8f);
    float4 a0 = ((const float4*)ns)[tid];
    float4 a1 = ((const float4*)ns)[tid + 256];
    float4 b0 = ((const float4*)ss)[tid];
    float4 b1 = ((const float4*)ss)[tid + 256];
    uint2 o0, o1;
    o0.x = pack2(v0.x * a0.x * b0.x * inv, v0.y * a0.y * b0.y * inv);
    o0.y = pack2(v0.z * a0.z * b0.z * inv, v0.w * a0.w * b0.w * inv);
    o1.x = pack2(v1.x * a1.x * b1.x * inv, v1.y * a1.y * b1.y * inv);
    o1.y = pack2(v1.z * a1.z * b1.z * inv, v1.w * a1.w * b1.w * inv);
    uint2* hr = (uint2*)(h + (size_t)bx * DIMS);
    hr[tid] = o0;
    hr[tid + 256] = o1;
  } else {
    const int cx = bx - 4096;
    const float* src;
    u16* dst;
    int i;
    if (cx < 4096) {
      src = Wq; dst = bqkv; i = cx;
    } else if (cx < 8192) {
      src = Wo; dst = bWo; i = cx - 4096;
    } else if (cx < 8448) {
      src = Wk; dst = bqkv + (size_t)2048 * 2048; i = cx - 8192;
    } else {
      src = Wv; dst = bqkv + (size_t)2176 * 2048; i = cx - 8448;
    }
    const int idx = i * 256 + tid;
    float4 v = ((const float4*)src)[idx];
    uint2 r;
    r.x = pack2(v.x, v.y);
    r.y = pack2(v.z, v.w);
    ((uint2*)dst)[idx] = r;
  }
}

// ---------------- C = A[M,K] * B[N,K]^T  (128x128 tile, 16x16x32 bf16 MFMA).
// Round-14: RESTORED to the round-12 (bench round 7) config -- best measured
// GEMM (294.3us total): 128x128 tile, BK=64 double-buffer, counted vmcnt(8),
// T2 XOR-swizzled LDS via pre-swizzled global source, T1 XCD chunked remap.
// Round-13's 128x64 / 4-blocks-per-CU variant regressed (298.1) -> GEMM is
// NOT occupancy-bound either; ~450 TF is this structure's plateau here.
// MODE 1: fp32 C = R + acc (residual epilogue, stride N).
// MODE 2: fused QKV: col-blocks 0..15 -> qb bf16 (stride DIMS);
//         col-block 16 -> kb packed attn K image (scaled by SCL2);
//         col-block 17 -> vtb packed attn V image.
template <int MODE>
__global__ __launch_bounds__(256) void gemm_bt(
    const u16* __restrict__ A, const u16* __restrict__ B, void* __restrict__ Cv,
    const float* __restrict__ R, u16* __restrict__ kb, u16* __restrict__ vtb,
    int M, int N, int K) {
  __shared__ u16 As[2][128 * 64];
  __shared__ u16 Bs[2][128 * 64];
  const int tid = threadIdx.x;
  const int lane = tid & 63;
  const int wv = tid >> 6;
  const int fr = lane & 15;
  const int fq = lane >> 4;

  // T1: XCD-aware chunked remap of the linear block id (bijective: nwg%8==0)
  const int gx = gridDim.x;
  const int nwg = gx * gridDim.y;
  const int id = blockIdx.y * gx + blockIdx.x;
  const int cpx = nwg >> 3;
  const int sid = (id & 7) * cpx + (id >> 3);
  const int m0 = (sid / gx) * 128;
  const int n0 = (sid % gx) * 128;

  const int wm = wv & 1;
  const int wn = wv >> 1;

  // staging: 32 rows x 64 cols per block-wide issue; 4 issues per matrix.
  // source column group is XOR-pre-swizzled so the LINEAR glds16 write
  // produces LDS[row][g] = M[row][g ^ (row&7)].
  const int srow = tid >> 3;                               // 0..31
  const int scol = (((tid & 7) ^ ((tid >> 3) & 7)) << 3);  // swizzled
  const u16* Ag[4];
  const u16* Bg[4];
#pragma unroll
  for (int i = 0; i < 4; ++i) {
    Ag[i] = A + (size_t)(m0 + i * 32 + srow) * K + scol;
    Bg[i] = B + (size_t)(n0 + i * 32 + srow) * K + scol;
  }

  f32x4 acc[4][4];
#pragma unroll
  for (int i = 0; i < 4; ++i)
#pragma unroll
    for (int j = 0; j < 4; ++j)
#pragma unroll
      for (int e = 0; e < 4; ++e) acc[i][j][e] = 0.0f;

#define GSTAGE(buf, kk0)                                    \
  {                                                         \
    _Pragma("unroll") for (int i = 0; i < 4; ++i) {         \
      glds16(Ag[i] + (kk0), &As[buf][i * 2048 + wv * 512]); \
      glds16(Bg[i] + (kk0), &Bs[buf][i * 2048 + wv * 512]); \
    }                                                       \
  }

#define GCOMP(buf)                                                            \
  {                                                                           \
    _Pragma("unroll") for (int kk = 0; kk < 2; ++kk) {                        \
      bf16x8 af_[4], bf_[4];                                                  \
      _Pragma("unroll") for (int i = 0; i < 4; ++i) {                         \
        af_[i] = *(const bf16x8*)(&As[buf][(wm * 64 + i * 16 + fr) * 64 +     \
                                           ((((kk << 2) | fq) ^ (fr & 7))     \
                                            << 3)]);                          \
        bf_[i] = *(const bf16x8*)(&Bs[buf][(wn * 64 + i * 16 + fr) * 64 +     \
                                           ((((kk << 2) | fq) ^ (fr & 7))     \
                                            << 3)]);                          \
      }                                                                       \
      _Pragma("unroll") for (int i = 0; i < 4; ++i)                           \
          _Pragma("unroll") for (int j = 0; j < 4; ++j) acc[i][j] =           \
          __builtin_amdgcn_mfma_f32_16x16x32_bf16(af_[i], bf_[j], acc[i][j],  \
                                                  0, 0, 0);                   \
    }                                                                         \
  }

  GSTAGE(0, 0);
  int k0 = 0;
  for (; k0 + 128 < K; k0 += 128) {
    GSTAGE(1, k0 + 64);
    asm volatile("s_waitcnt vmcnt(8)\ns_barrier" ::: "memory");
    GCOMP(0);
    asm volatile("s_barrier" ::: "memory");
    GSTAGE(0, k0 + 128);
    asm volatile("s_waitcnt vmcnt(8)\ns_barrier" ::: "memory");
    GCOMP(1);
    asm volatile("s_barrier" ::: "memory");
  }
  // tail: k0 == K-128
  GSTAGE(1, k0 + 64);
  asm volatile("s_waitcnt vmcnt(8)\ns_barrier" ::: "memory");
  GCOMP(0);
  asm volatile("s_barrier" ::: "memory");
  asm volatile("s_waitcnt vmcnt(0)\ns_barrier" ::: "memory");
  GCOMP(1);
#undef GSTAGE
#undef GCOMP

#pragma unroll
  for (int i = 0; i < 4; ++i) {
    const int m = m0 + wm * 64 + i * 16 + fq * 4;
#pragma unroll
    for (int j = 0; j < 4; ++j) {
      const int n = n0 + wn * 64 + j * 16 + fr;
#pragma unroll
      for (int r = 0; r < 4; ++r) {
        if (MODE == 1) {
          const size_t idx = (size_t)(m + r) * N + n;
          ((float*)Cv)[idx] = R[idx] + acc[i][j][r];
        } else {
          if (n0 < 2048) {
            ((u16*)Cv)[(size_t)(m + r) * DIMS + n] = f2bf(acc[i][j][r]);
          } else {
            const int token = m + r;
            const int bb = token >> 11;     // batch
            const int srw = token & 2047;
            const int t = srw >> 6;         // kv tile
            const int rowin = srw & 63;     // key index inside tile
            if (n0 < 2176) {
              // K pack: pos = kk^{-1}(rowin); column (c,j) from dh-offset dd.
              const int d = n - 2048;
              const int gg = d >> 6;
              const int dd = d & 63;
              const int c = ((dd >> 5) << 2) | ((dd >> 3) & 3);
              const int jj = dd & 7;
              const int pos = (rowin & 32) | ((rowin & 4) << 2) |
                              ((rowin & 0x18) >> 1) | (rowin & 3);
              kb[(((size_t)(bb * NG + gg) * 32 + t) * 8 + c) * 512 + pos * 8 +
                 jj] = f2bf(acc[i][j][r] * SCL2);
            } else {
              // V pack: column c = key-octet, entry d = dh index.
              const int d = n - 2176;
              const int gg = d >> 6;
              const int dv = d & 63;
              const int c = rowin >> 3;
              const int jj = rowin & 7;
              vtb[(((size_t)(bb * NG + gg) * 32 + t) * 8 + c) * 512 + dv * 8 +
                  jj] = f2bf(acc[i][j][r]);
            }
          }
        }
      }
    }
  }
}

// ---------------- flash attention, GQA, fixed-max softmax (exact: |sv|<<120).
// S^T = K Q^T with PERMUTED K-row staging: the C-layout of two 16-key chunks
// concatenates directly into the K=32 PV A-fragment (k = fq*8+j).
// Round-14 attn: 4-buffer ring, 2 tiles per barrier pair. Per 2 tiles:
// 1 vmcnt wait + 2 barriers (was 2 waits + 4 barriers), and each tile's
// loads land TWO compute phases after issue. Tests the hypothesis that the
// ~50% dead time (6.7kcy wall vs ~3kcy pipe demand per tile) is barrier
// convoy frequency. COMPUTE/STAGE bodies are the proven round-8 code,
// UNCHANGED. Cost: LDS 64KB -> 2 blocks/CU (round 0->1 measured 2 vs 4
// blocks/CU as neutral for attn, so the occupancy risk is bounded).
__global__ __launch_bounds__(256, 2) void attn_kernel(
    const u16* __restrict__ q, const u16* __restrict__ kbuf,
    const u16* __restrict__ vT, u16* __restrict__ out) {
  __shared__ u16 Ks[4][8 * 512];  // [buf][c=dh-octet][pos 0..63][8] permuted
  __shared__ u16 Vs[4][8 * 512];  // [buf][c=key-octet][d 0..63][8]
  const int tid = threadIdx.x;
  const int lane = tid & 63;
  const int wv = tid >> 6;  // 0..3
  const int fr = lane & 15;
  const int fq = lane >> 4;
  const int b = blockIdx.x >> 5;
  const int hq = blockIdx.x & 31;
  const int g = hq >> 4;  // 16 query heads per KV group
  const int q0 = blockIdx.y * 128 + wv * 32;

  // Q fragments (B-operand layout: n=query=fr, k=dh=fq*8+j), loaded once.
  bf16x8 af[2][2];
#pragma unroll
  for (int mt = 0; mt < 2; ++mt)
#pragma unroll
    for (int kx = 0; kx < 2; ++kx)
      af[mt][kx] =
          *(const bf16x8*)(q + (size_t)(b * SEQ + q0 + mt * 16 + fr) * DIMS +
                           hq * DH + kx * 32 + fq * 8);

  f32x4 Oa[2][4];
  f32x4 On[2];  // row-sum accumulator (ones-B MFMA), same layout as Oa
#pragma unroll
  for (int mt = 0; mt < 2; ++mt) {
#pragma unroll
    for (int e = 0; e < 4; ++e) On[mt][e] = 0.0f;
#pragma unroll
    for (int j = 0; j < 4; ++j)
#pragma unroll
      for (int e = 0; e < 4; ++e) Oa[mt][j][e] = 0.0f;
  }

  bf16x8 onev;
#pragma unroll
  for (int e = 0; e < 8; ++e) onev[e] = (__bf16)1.0f;

  // pre-packed panels: [(b,g)][tile][c][512] u16, fully contiguous per tile
  const u16* ksrc = kbuf + (size_t)(b * NG + g) * 32 * 4096;
  const u16* vsrc = vT + (size_t)(b * NG + g) * 32 * 4096;

  // each wave stages 2 K-columns + 2 V-columns per tile (4 glds16, 1KB each)
  const int c0 = wv * 2;
#define STAGE(buf, tile)                                          \
  {                                                               \
    const size_t tb_ = (size_t)(tile)*4096;                       \
    _Pragma("unroll") for (int s = 0; s < 2; ++s) {               \
      const int c = c0 + s;                                       \
      glds16(ksrc + tb_ + c * 512 + lane * 8, &Ks[buf][c * 512]); \
      glds16(vsrc + tb_ + c * 512 + lane * 8, &Vs[buf][c * 512]); \
    }                                                             \
  }

#define COMPUTE(buf)                                                          \
  {                                                                           \
    _Pragma("unroll") for (int kg = 0; kg < 2; ++kg) {                        \
      bf16x8 kf00 = *(const bf16x8*)(&Ks[buf][fq * 512 + (kg * 32 + fr) * 8]); \
      bf16x8 kf01 =                                                           \
          *(const bf16x8*)(&Ks[buf][(4 + fq) * 512 + (kg * 32 + fr) * 8]);    \
      bf16x8 kf10 =                                                           \
          *(const bf16x8*)(&Ks[buf][fq * 512 + (kg * 32 + 16 + fr) * 8]);     \
      bf16x8 kf11 = *(const bf16x8*)(&Ks[buf][(4 + fq) * 512 +                \
                                              (kg * 32 + 16 + fr) * 8]);      \
      bf16x8 vf[4];                                                           \
      _Pragma("unroll") for (int jt = 0; jt < 4; ++jt) vf[jt] =               \
          *(const bf16x8*)(&Vs[buf][(kg * 4 + fq) * 512 + (jt * 16 + fr) * 8]); \
      _Pragma("unroll") for (int mt = 0; mt < 2; ++mt) {                      \
        f32x4 s0 = {0.0f, 0.0f, 0.0f, 0.0f};                                  \
        f32x4 s1 = {0.0f, 0.0f, 0.0f, 0.0f};                                  \
        s0 = __builtin_amdgcn_mfma_f32_16x16x32_bf16(kf00, af[mt][0], s0, 0,  \
                                                     0, 0);                   \
        s0 = __builtin_amdgcn_mfma_f32_16x16x32_bf16(kf01, af[mt][1], s0, 0,  \
                                                     0, 0);                   \
        s1 = __builtin_amdgcn_mfma_f32_16x16x32_bf16(kf10, af[mt][0], s1, 0,  \
                                                     0, 0);                   \
        s1 = __builtin_amdgcn_mfma_f32_16x16x32_bf16(kf11, af[mt][1], s1, 0,  \
                                                     0, 0);                   \
        const float p0 = __builtin_amdgcn_exp2f(s0[0]);                       \
        const float p1 = __builtin_amdgcn_exp2f(s0[1]);                       \
        const float p2 = __builtin_amdgcn_exp2f(s0[2]);                       \
        const float p3 = __builtin_amdgcn_exp2f(s0[3]);                       \
        const float p4 = __builtin_amdgcn_exp2f(s1[0]);                       \
        const float p5 = __builtin_amdgcn_exp2f(s1[1]);                       \
        const float p6 = __builtin_amdgcn_exp2f(s1[2]);                       \
        const float p7 = __builtin_amdgcn_exp2f(s1[3]);                       \
        union {                                                               \
          bf16x8 v;                                                           \
          u32 u[4];                                                           \
        } pu;                                                                 \
        pu.u[0] = cvtpk(p0, p1);                                              \
        pu.u[1] = cvtpk(p2, p3);                                              \
        pu.u[2] = cvtpk(p4, p5);                                              \
        pu.u[3] = cvtpk(p6, p7);                                              \
        _Pragma("unroll") for (int jt = 0; jt < 4; ++jt) Oa[mt][jt] =         \
            __builtin_amdgcn_mfma_f32_16x16x32_bf16(pu.v, vf[jt], Oa[mt][jt], \
                                                    0, 0, 0);                 \
        On[mt] = __builtin_amdgcn_mfma_f32_16x16x32_bf16(pu.v, onev, On[mt],  \
                                                         0, 0, 0);            \
      }                                                                       \
    }                                                                         \
  }

  STAGE(0, 0);
  STAGE(1, 1);
  for (int it = 0; it < 32; it += 4) {
    STAGE(2, (it + 2) & 31);
    STAGE(3, (it + 3) & 31);
    // wait for tiles it/it+1 (8 loads, issued two compute phases ago);
    // keep the 8 loads of tiles it+2/it+3 in flight across the barriers.
    asm volatile("s_waitcnt vmcnt(8)\ns_barrier" ::: "memory");
    COMPUTE(0);
    COMPUTE(1);
    asm volatile("s_barrier" ::: "memory");
    STAGE(0, (it + 4) & 31);
    STAGE(1, (it + 5) & 31);
    asm volatile("s_waitcnt vmcnt(8)\ns_barrier" ::: "memory");
    COMPUTE(2);
    COMPUTE(3);
    asm volatile("s_barrier" ::: "memory");
  }
#undef STAGE
#undef COMPUTE

#pragma unroll
  for (int mt = 0; mt < 2; ++mt)
#pragma unroll
    for (int r = 0; r < 4; ++r) {
      const float invl = 1.0f / On[mt][r];
      const int row = q0 + mt * 16 + fq * 4 + r;
#pragma unroll
      for (int jt = 0; jt < 4; ++jt)
        out[(size_t)(b * SEQ + row) * DIMS + hq * DH + jt * 16 + fr] =
            f2bf(Oa[mt][jt][r] * invl);
    }
}

extern "C" void kernel_launch(void* const* d_in, const int* in_sizes, int n_in,
                              void* d_out, int out_size, void* d_ws,
                              size_t ws_size, hipStream_t stream) {
  const float* x = (const float*)d_in[0];
  const float* ns = (const float*)d_in[1];
  const float* ssc = (const float*)d_in[2];
  const float* Wq = (const float*)d_in[3];
  const float* Wk = (const float*)d_in[4];
  const float* Wv = (const float*)d_in[5];
  const float* Wo = (const float*)d_in[6];

  char* ws = (char*)d_ws;
  u16* hbuf = (u16*)(ws);            // [4096][2048] bf16        16 MB
  u16* bqkv = (u16*)(ws + 16777216); // [2304][2048] Wq|Wk|Wv    9 MB
  u16* bWo = (u16*)(ws + 26214400);  // [2048][2048]              8 MB
  u16* qb = (u16*)(ws + 34603008);   // [4096][2048]             16 MB
  u16* kb = (u16*)(ws + 51380224);   // kp[(b,g)][32][8][512]     1 MB
  u16* vtb = (u16*)(ws + 52428800);  // vp[(b,g)][32][8][512]     1 MB
  u16* ab = (u16*)(ws + 53477376);   // [4096][2048]             16 MB

  // rms (blocks 0..4095) + weight cvt (blocks 4096..12799), one dispatch
  prep_kernel<<<dim3(12800), dim3(256), 0, stream>>>(x, ns, ssc, hbuf, Wq, Wo,
                                                     Wk, Wv, bqkv, bWo);

  // fused q/k/v projections: qb = h Wq^T, kb/vtb = packed attn staging panels
  gemm_bt<2><<<dim3(18, 32), dim3(256), 0, stream>>>(
      hbuf, bqkv, qb, nullptr, kb, vtb, 4096, 2048, 2048);
  attn_kernel<<<dim3(64, 16), dim3(256), 0, stream>>>(qb, kb, vtb, ab);
  // out = x + attn Wo^T
  gemm_bt<1><<<dim3(16, 32), dim3(256), 0, stream>>>(
      ab, bWo, d_out, x, nullptr, nullptr, 4096, 2048, 2048);
}

// Round 11
// 293.905 us; speedup vs baseline: 1.0252x; 1.0252x over previous
//
#include <hip/hip_runtime.h>

typedef unsigned short u16;
typedef unsigned int u32;
typedef __bf16 bf16x8 __attribute__((ext_vector_type(8)));
typedef float f32x4 __attribute__((ext_vector_type(4)));

#define DIMS 2048
#define SEQ 2048
#define BATCH 2
#define NH 32
#define NG 2
#define DH 64
#define MROWS (BATCH * SEQ)  /* 4096 */
#define KVD (NG * DH)        /* 128 */

#define SCL2 (0.125f * 1.44269504088896f) /* 1/sqrt(64) * log2(e) */

__device__ __forceinline__ u16 f2bf(float f) {
  u32 u = __float_as_uint(f);
  u32 r = u + 0x7fffu + ((u >> 16) & 1u);
  return (u16)(r >> 16);
}
__device__ __forceinline__ u32 pack2(float a, float b) {
  return (u32)f2bf(a) | ((u32)f2bf(b) << 16);
}
// packed f32->bf16x2 (RNE), single instruction on gfx950
__device__ __forceinline__ u32 cvtpk(float a, float b) {
#if __has_builtin(__builtin_amdgcn_cvt_pk_bf16_f32)
  typedef __bf16 bf16x2 __attribute__((ext_vector_type(2)));
  union {
    bf16x2 v;
    u32 u;
  } r;
  r.v = __builtin_amdgcn_cvt_pk_bf16_f32(a, b);
  return r.u;
#else
  return pack2(a, b);
#endif
}
// async global->LDS, 16B/lane. LDS dest = wave-uniform base + lane*16;
// global source address is PER-LANE (vector address).
__device__ __forceinline__ void glds16(const u16* g, u16* l) {
  __builtin_amdgcn_global_load_lds(
      (const __attribute__((address_space(1))) void*)g,
      (__attribute__((address_space(3))) void*)l, 16, 0, 0);
}

// ---------------- prep: RMS_split pre-norm (blocks 0..4095) + fp32->bf16
// weight conversion (blocks 4096..12799) in ONE dispatch.
__global__ __launch_bounds__(256) void prep_kernel(
    const float* __restrict__ x, const float* __restrict__ ns,
    const float* __restrict__ ss, u16* __restrict__ h,
    const float* __restrict__ Wq, const float* __restrict__ Wo,
    const float* __restrict__ Wk, const float* __restrict__ Wv,
    u16* __restrict__ bqkv, u16* __restrict__ bWo) {
  const int bx = blockIdx.x;
  const int tid = threadIdx.x;
  if (bx < 4096) {
    // RMS_split: h = bf16( ns*x/(||x||/sqrt(d)+eps)*ss )
    const float* xr = x + (size_t)bx * DIMS;
    float4 v0 = ((const float4*)xr)[tid];
    float4 v1 = ((const float4*)xr)[tid + 256];
    float s = v0.x * v0.x + v0.y * v0.y + v0.z * v0.z + v0.w * v0.w +
              v1.x * v1.x + v1.y * v1.y + v1.z * v1.z + v1.w * v1.w;
#pragma unroll
    for (int d = 1; d < 64; d <<= 1) s += __shfl_xor(s, d, 64);
    __shared__ float red[4];
    if ((tid & 63) == 0) red[tid >> 6] = s;
    __syncthreads();
    float tot = red[0] + red[1] + red[2] + red[3];
    float inv = 1.0f / (sqrtf(tot * (1.0f / DIMS)) + 1e-8f);
    float4 a0 = ((const float4*)ns)[tid];
    float4 a1 = ((const float4*)ns)[tid + 256];
    float4 b0 = ((const float4*)ss)[tid];
    float4 b1 = ((const float4*)ss)[tid + 256];
    uint2 o0, o1;
    o0.x = pack2(v0.x * a0.x * b0.x * inv, v0.y * a0.y * b0.y * inv);
    o0.y = pack2(v0.z * a0.z * b0.z * inv, v0.w * a0.w * b0.w * inv);
    o1.x = pack2(v1.x * a1.x * b1.x * inv, v1.y * a1.y * b1.y * inv);
    o1.y = pack2(v1.z * a1.z * b1.z * inv, v1.w * a1.w * b1.w * inv);
    uint2* hr = (uint2*)(h + (size_t)bx * DIMS);
    hr[tid] = o0;
    hr[tid + 256] = o1;
  } else {
    const int cx = bx - 4096;
    const float* src;
    u16* dst;
    int i;
    if (cx < 4096) {
      src = Wq; dst = bqkv; i = cx;
    } else if (cx < 8192) {
      src = Wo; dst = bWo; i = cx - 4096;
    } else if (cx < 8448) {
      src = Wk; dst = bqkv + (size_t)2048 * 2048; i = cx - 8192;
    } else {
      src = Wv; dst = bqkv + (size_t)2176 * 2048; i = cx - 8448;
    }
    const int idx = i * 256 + tid;
    float4 v = ((const float4*)src)[idx];
    uint2 r;
    r.x = pack2(v.x, v.y);
    r.y = pack2(v.z, v.w);
    ((uint2*)dst)[idx] = r;
  }
}

// ---------------- C = A[M,K] * B[N,K]^T  (128x128 tile, 16x16x32 bf16 MFMA).
// Best measured GEMM config (bench round 7, 294.3us total): 128x128 tile,
// BK=64 double-buffer, counted vmcnt(8), T2 XOR-swizzled LDS via
// pre-swizzled global source, T1 XCD chunked remap. Subsequent experiments
// (128x64 4-blocks/CU r8; BK32 5-resident r6) all land at the same ~450 TF
// plateau -> structure-level ceiling at this problem shape (m233: the
// stage+vmcnt+barrier joint overhead; no single-factor fix moves it).
// MODE 1: fp32 C = R + acc (residual epilogue, stride N).
// MODE 2: fused QKV: col-blocks 0..15 -> qb bf16 (stride DIMS);
//         col-block 16 -> kb packed attn K image (scaled by SCL2);
//         col-block 17 -> vtb packed attn V image.
template <int MODE>
__global__ __launch_bounds__(256) void gemm_bt(
    const u16* __restrict__ A, const u16* __restrict__ B, void* __restrict__ Cv,
    const float* __restrict__ R, u16* __restrict__ kb, u16* __restrict__ vtb,
    int M, int N, int K) {
  __shared__ u16 As[2][128 * 64];
  __shared__ u16 Bs[2][128 * 64];
  const int tid = threadIdx.x;
  const int lane = tid & 63;
  const int wv = tid >> 6;
  const int fr = lane & 15;
  const int fq = lane >> 4;

  // T1: XCD-aware chunked remap of the linear block id (bijective: nwg%8==0)
  const int gx = gridDim.x;
  const int nwg = gx * gridDim.y;
  const int id = blockIdx.y * gx + blockIdx.x;
  const int cpx = nwg >> 3;
  const int sid = (id & 7) * cpx + (id >> 3);
  const int m0 = (sid / gx) * 128;
  const int n0 = (sid % gx) * 128;

  const int wm = wv & 1;
  const int wn = wv >> 1;

  // staging: 32 rows x 64 cols per block-wide issue; 4 issues per matrix.
  // source column group is XOR-pre-swizzled so the LINEAR glds16 write
  // produces LDS[row][g] = M[row][g ^ (row&7)].
  const int srow = tid >> 3;                               // 0..31
  const int scol = (((tid & 7) ^ ((tid >> 3) & 7)) << 3);  // swizzled
  const u16* Ag[4];
  const u16* Bg[4];
#pragma unroll
  for (int i = 0; i < 4; ++i) {
    Ag[i] = A + (size_t)(m0 + i * 32 + srow) * K + scol;
    Bg[i] = B + (size_t)(n0 + i * 32 + srow) * K + scol;
  }

  f32x4 acc[4][4];
#pragma unroll
  for (int i = 0; i < 4; ++i)
#pragma unroll
    for (int j = 0; j < 4; ++j)
#pragma unroll
      for (int e = 0; e < 4; ++e) acc[i][j][e] = 0.0f;

#define GSTAGE(buf, kk0)                                    \
  {                                                         \
    _Pragma("unroll") for (int i = 0; i < 4; ++i) {         \
      glds16(Ag[i] + (kk0), &As[buf][i * 2048 + wv * 512]); \
      glds16(Bg[i] + (kk0), &Bs[buf][i * 2048 + wv * 512]); \
    }                                                       \
  }

#define GCOMP(buf)                                                            \
  {                                                                           \
    _Pragma("unroll") for (int kk = 0; kk < 2; ++kk) {                        \
      bf16x8 af_[4], bf_[4];                                                  \
      _Pragma("unroll") for (int i = 0; i < 4; ++i) {                         \
        af_[i] = *(const bf16x8*)(&As[buf][(wm * 64 + i * 16 + fr) * 64 +     \
                                           ((((kk << 2) | fq) ^ (fr & 7))     \
                                            << 3)]);                          \
        bf_[i] = *(const bf16x8*)(&Bs[buf][(wn * 64 + i * 16 + fr) * 64 +     \
                                           ((((kk << 2) | fq) ^ (fr & 7))     \
                                            << 3)]);                          \
      }                                                                       \
      _Pragma("unroll") for (int i = 0; i < 4; ++i)                           \
          _Pragma("unroll") for (int j = 0; j < 4; ++j) acc[i][j] =           \
          __builtin_amdgcn_mfma_f32_16x16x32_bf16(af_[i], bf_[j], acc[i][j],  \
                                                  0, 0, 0);                   \
    }                                                                         \
  }

  GSTAGE(0, 0);
  int k0 = 0;
  for (; k0 + 128 < K; k0 += 128) {
    GSTAGE(1, k0 + 64);
    asm volatile("s_waitcnt vmcnt(8)\ns_barrier" ::: "memory");
    GCOMP(0);
    asm volatile("s_barrier" ::: "memory");
    GSTAGE(0, k0 + 128);
    asm volatile("s_waitcnt vmcnt(8)\ns_barrier" ::: "memory");
    GCOMP(1);
    asm volatile("s_barrier" ::: "memory");
  }
  // tail: k0 == K-128
  GSTAGE(1, k0 + 64);
  asm volatile("s_waitcnt vmcnt(8)\ns_barrier" ::: "memory");
  GCOMP(0);
  asm volatile("s_barrier" ::: "memory");
  asm volatile("s_waitcnt vmcnt(0)\ns_barrier" ::: "memory");
  GCOMP(1);
#undef GSTAGE
#undef GCOMP

#pragma unroll
  for (int i = 0; i < 4; ++i) {
    const int m = m0 + wm * 64 + i * 16 + fq * 4;
#pragma unroll
    for (int j = 0; j < 4; ++j) {
      const int n = n0 + wn * 64 + j * 16 + fr;
#pragma unroll
      for (int r = 0; r < 4; ++r) {
        if (MODE == 1) {
          const size_t idx = (size_t)(m + r) * N + n;
          ((float*)Cv)[idx] = R[idx] + acc[i][j][r];
        } else {
          if (n0 < 2048) {
            ((u16*)Cv)[(size_t)(m + r) * DIMS + n] = f2bf(acc[i][j][r]);
          } else {
            const int token = m + r;
            const int bb = token >> 11;     // batch
            const int srw = token & 2047;
            const int t = srw >> 6;         // kv tile
            const int rowin = srw & 63;     // key index inside tile
            if (n0 < 2176) {
              // K pack: pos = kk^{-1}(rowin); column (c,j) from dh-offset dd.
              const int d = n - 2048;
              const int gg = d >> 6;
              const int dd = d & 63;
              const int c = ((dd >> 5) << 2) | ((dd >> 3) & 3);
              const int jj = dd & 7;
              const int pos = (rowin & 32) | ((rowin & 4) << 2) |
                              ((rowin & 0x18) >> 1) | (rowin & 3);
              kb[(((size_t)(bb * NG + gg) * 32 + t) * 8 + c) * 512 + pos * 8 +
                 jj] = f2bf(acc[i][j][r] * SCL2);
            } else {
              // V pack: column c = key-octet, entry d = dh index.
              const int d = n - 2176;
              const int gg = d >> 6;
              const int dv = d & 63;
              const int c = rowin >> 3;
              const int jj = rowin & 7;
              vtb[(((size_t)(bb * NG + gg) * 32 + t) * 8 + c) * 512 + dv * 8 +
                  jj] = f2bf(acc[i][j][r]);
            }
          }
        }
      }
    }
  }
}

// ---------------- flash attention, GQA, fixed-max softmax (exact: |sv|<<120).
// S^T = K Q^T with PERMUTED K-row staging: the C-layout of two 16-key chunks
// concatenates directly into the K=32 PV A-fragment (k = fq*8+j).
// Best measured structure (87.5us): K/V pre-packed by gemm_bt<2>,
// contiguous 1KB glds16, 2-buffer + vmcnt(4), 4 blocks/CU.
// Refuted variants: 3-buf+micro-setprio (r4, 96.6), split QK chains (r5,
// 94.7), 4-buf/2-tiles-per-barrier @2 blocks/CU (r9, 94.6).
// Round-16 (resubmit of round-15; that bench died of container-infra flake,
// same symptom as round 3 -> resubmit unchanged): ONE s_setprio(1)/(0) pair
// around each WHOLE COMPUTE phase (2 toggles/tile vs r4's 16 -- preserves
// compiler's intra-phase interleave). T5 prerequisite holds: 4 independent
// blocks/CU give phase-diverse waves (m191: +4-7% on attn in this regime).
__global__ __launch_bounds__(256, 4) void attn_kernel(
    const u16* __restrict__ q, const u16* __restrict__ kbuf,
    const u16* __restrict__ vT, u16* __restrict__ out) {
  __shared__ u16 Ks[2][8 * 512];  // [buf][c=dh-octet][pos 0..63][8] permuted
  __shared__ u16 Vs[2][8 * 512];  // [buf][c=key-octet][d 0..63][8]
  const int tid = threadIdx.x;
  const int lane = tid & 63;
  const int wv = tid >> 6;  // 0..3
  const int fr = lane & 15;
  const int fq = lane >> 4;
  const int b = blockIdx.x >> 5;
  const int hq = blockIdx.x & 31;
  const int g = hq >> 4;  // 16 query heads per KV group
  const int q0 = blockIdx.y * 128 + wv * 32;

  // Q fragments (B-operand layout: n=query=fr, k=dh=fq*8+j), loaded once.
  bf16x8 af[2][2];
#pragma unroll
  for (int mt = 0; mt < 2; ++mt)
#pragma unroll
    for (int kx = 0; kx < 2; ++kx)
      af[mt][kx] =
          *(const bf16x8*)(q + (size_t)(b * SEQ + q0 + mt * 16 + fr) * DIMS +
                           hq * DH + kx * 32 + fq * 8);

  f32x4 Oa[2][4];
  f32x4 On[2];  // row-sum accumulator (ones-B MFMA), same layout as Oa
#pragma unroll
  for (int mt = 0; mt < 2; ++mt) {
#pragma unroll
    for (int e = 0; e < 4; ++e) On[mt][e] = 0.0f;
#pragma unroll
    for (int j = 0; j < 4; ++j)
#pragma unroll
      for (int e = 0; e < 4; ++e) Oa[mt][j][e] = 0.0f;
  }

  bf16x8 onev;
#pragma unroll
  for (int e = 0; e < 8; ++e) onev[e] = (__bf16)1.0f;

  // pre-packed panels: [(b,g)][tile][c][512] u16, fully contiguous per tile
  const u16* ksrc = kbuf + (size_t)(b * NG + g) * 32 * 4096;
  const u16* vsrc = vT + (size_t)(b * NG + g) * 32 * 4096;

  // each wave stages 2 K-columns + 2 V-columns per tile (4 glds16, 1KB each)
  const int c0 = wv * 2;
#define STAGE(buf, tile)                                          \
  {                                                               \
    const size_t tb_ = (size_t)(tile)*4096;                       \
    _Pragma("unroll") for (int s = 0; s < 2; ++s) {               \
      const int c = c0 + s;                                       \
      glds16(ksrc + tb_ + c * 512 + lane * 8, &Ks[buf][c * 512]); \
      glds16(vsrc + tb_ + c * 512 + lane * 8, &Vs[buf][c * 512]); \
    }                                                             \
  }

#define COMPUTE(buf)                                                          \
  {                                                                           \
    _Pragma("unroll") for (int kg = 0; kg < 2; ++kg) {                        \
      bf16x8 kf00 = *(const bf16x8*)(&Ks[buf][fq * 512 + (kg * 32 + fr) * 8]); \
      bf16x8 kf01 =                                                           \
          *(const bf16x8*)(&Ks[buf][(4 + fq) * 512 + (kg * 32 + fr) * 8]);    \
      bf16x8 kf10 =                                                           \
          *(const bf16x8*)(&Ks[buf][fq * 512 + (kg * 32 + 16 + fr) * 8]);     \
      bf16x8 kf11 = *(const bf16x8*)(&Ks[buf][(4 + fq) * 512 +                \
                                              (kg * 32 + 16 + fr) * 8]);      \
      bf16x8 vf[4];                                                           \
      _Pragma("unroll") for (int jt = 0; jt < 4; ++jt) vf[jt] =               \
          *(const bf16x8*)(&Vs[buf][(kg * 4 + fq) * 512 + (jt * 16 + fr) * 8]); \
      _Pragma("unroll") for (int mt = 0; mt < 2; ++mt) {                      \
        f32x4 s0 = {0.0f, 0.0f, 0.0f, 0.0f};                                  \
        f32x4 s1 = {0.0f, 0.0f, 0.0f, 0.0f};                                  \
        s0 = __builtin_amdgcn_mfma_f32_16x16x32_bf16(kf00, af[mt][0], s0, 0,  \
                                                     0, 0);                   \
        s0 = __builtin_amdgcn_mfma_f32_16x16x32_bf16(kf01, af[mt][1], s0, 0,  \
                                                     0, 0);                   \
        s1 = __builtin_amdgcn_mfma_f32_16x16x32_bf16(kf10, af[mt][0], s1, 0,  \
                                                     0, 0);                   \
        s1 = __builtin_amdgcn_mfma_f32_16x16x32_bf16(kf11, af[mt][1], s1, 0,  \
                                                     0, 0);                   \
        const float p0 = __builtin_amdgcn_exp2f(s0[0]);                       \
        const float p1 = __builtin_amdgcn_exp2f(s0[1]);                       \
        const float p2 = __builtin_amdgcn_exp2f(s0[2]);                       \
        const float p3 = __builtin_amdgcn_exp2f(s0[3]);                       \
        const float p4 = __builtin_amdgcn_exp2f(s1[0]);                       \
        const float p5 = __builtin_amdgcn_exp2f(s1[1]);                       \
        const float p6 = __builtin_amdgcn_exp2f(s1[2]);                       \
        const float p7 = __builtin_amdgcn_exp2f(s1[3]);                       \
        union {                                                               \
          bf16x8 v;                                                           \
          u32 u[4];                                                           \
        } pu;                                                                 \
        pu.u[0] = cvtpk(p0, p1);                                              \
        pu.u[1] = cvtpk(p2, p3);                                              \
        pu.u[2] = cvtpk(p4, p5);                                              \
        pu.u[3] = cvtpk(p6, p7);                                              \
        _Pragma("unroll") for (int jt = 0; jt < 4; ++jt) Oa[mt][jt] =         \
            __builtin_amdgcn_mfma_f32_16x16x32_bf16(pu.v, vf[jt], Oa[mt][jt], \
                                                    0, 0, 0);                 \
        On[mt] = __builtin_amdgcn_mfma_f32_16x16x32_bf16(pu.v, onev, On[mt],  \
                                                         0, 0, 0);            \
      }                                                                       \
    }                                                                         \
  }

  STAGE(0, 0);
  for (int it = 0; it < 32; it += 2) {
    STAGE(1, (it + 1) & 31);
    asm volatile("s_waitcnt vmcnt(4)\ns_barrier" ::: "memory");
    __builtin_amdgcn_s_setprio(1);
    COMPUTE(0);
    __builtin_amdgcn_s_setprio(0);
    asm volatile("s_barrier" ::: "memory");
    STAGE(0, (it + 2) & 31);
    asm volatile("s_waitcnt vmcnt(4)\ns_barrier" ::: "memory");
    __builtin_amdgcn_s_setprio(1);
    COMPUTE(1);
    __builtin_amdgcn_s_setprio(0);
    asm volatile("s_barrier" ::: "memory");
  }
#undef STAGE
#undef COMPUTE

#pragma unroll
  for (int mt = 0; mt < 2; ++mt)
#pragma unroll
    for (int r = 0; r < 4; ++r) {
      const float invl = 1.0f / On[mt][r];
      const int row = q0 + mt * 16 + fq * 4 + r;
#pragma unroll
      for (int jt = 0; jt < 4; ++jt)
        out[(size_t)(b * SEQ + row) * DIMS + hq * DH + jt * 16 + fr] =
            f2bf(Oa[mt][jt][r] * invl);
    }
}

extern "C" void kernel_launch(void* const* d_in, const int* in_sizes, int n_in,
                              void* d_out, int out_size, void* d_ws,
                              size_t ws_size, hipStream_t stream) {
  const float* x = (const float*)d_in[0];
  const float* ns = (const float*)d_in[1];
  const float* ssc = (const float*)d_in[2];
  const float* Wq = (const float*)d_in[3];
  const float* Wk = (const float*)d_in[4];
  const float* Wv = (const float*)d_in[5];
  const float* Wo = (const float*)d_in[6];

  char* ws = (char*)d_ws;
  u16* hbuf = (u16*)(ws);            // [4096][2048] bf16        16 MB
  u16* bqkv = (u16*)(ws + 16777216); // [2304][2048] Wq|Wk|Wv    9 MB
  u16* bWo = (u16*)(ws + 26214400);  // [2048][2048]              8 MB
  u16* qb = (u16*)(ws + 34603008);   // [4096][2048]             16 MB
  u16* kb = (u16*)(ws + 51380224);   // kp[(b,g)][32][8][512]     1 MB
  u16* vtb = (u16*)(ws + 52428800);  // vp[(b,g)][32][8][512]     1 MB
  u16* ab = (u16*)(ws + 53477376);   // [4096][2048]             16 MB

  // rms (blocks 0..4095) + weight cvt (blocks 4096..12799), one dispatch
  prep_kernel<<<dim3(12800), dim3(256), 0, stream>>>(x, ns, ssc, hbuf, Wq, Wo,
                                                     Wk, Wv, bqkv, bWo);

  // fused q/k/v projections: qb = h Wq^T, kb/vtb = packed attn staging panels
  gemm_bt<2><<<dim3(18, 32), dim3(256), 0, stream>>>(
      hbuf, bqkv, qb, nullptr, kb, vtb, 4096, 2048, 2048);
  attn_kernel<<<dim3(64, 16), dim3(256), 0, stream>>>(qb, kb, vtb, ab);
  // out = x + attn Wo^T
  gemm_bt<1><<<dim3(16, 32), dim3(256), 0, stream>>>(
      ab, bWo, d_out, x, nullptr, nullptr, 4096, 2048, 2048);
}